// Round 2
// 237.902 us; speedup vs baseline: 1.0815x; 1.0815x over previous
//
#include <hip/hip_runtime.h>
#include <hip/hip_bf16.h>
#include <math.h>

// IDSCT2: out[b,u,v] = sum_{p,q} x[b,p,q] * S[u,p] * C[v,q]
// Two bf16-MFMA NT GEMMs per batch:
//   pass1: tT[b][v][p] = sum_q C[v][q] * xb[b][p][q]     (A=C, B=x[b])
//   pass2: out[b][u][v] = sum_p S[u][p] * tT[b][v][p]    (A=S, B=tT[b])
//
// R7 (= R6 hardened): 256x256 8-phase counted-vmcnt template (T3+T4+T5).
// BK=64, 512 thr = 8 waves (2x4), each wave owns 128x64 of C (8x4 frags
// of 16x16x32). Double-buffered 128 KiB LDS. Per 8-phase iter: 2 K-tiles;
// each phase = {ds-read frag subtile, issue one half-tile stage (2x glds),
// s_barrier, lgkmcnt(0)+sched_barrier(0), setprio(1)+16 MFMA+setprio(0),
// s_barrier}. vmcnt(6) ONLY at phases 4/8 (3 half-tiles = 6 glds in
// flight across barriers -- never drained in the main loop).
// Fixes vs R6: (a) rule #18 -- __builtin_amdgcn_sched_barrier(0) after
// every lgkmcnt(0) so hipcc cannot hoist register-only MFMAs above the
// wait; (b) explicitly wave-uniform LDS dest for global_load_lds
// (wave*512 elems) instead of per-lane tid*8 (same address, no
// readfirstlane assumption).
// Swizzle (both-sides, rule #21): LDS row-major [row][64], 16B chunk
// slot cs of row r holds global chunk cs^(r&7); staged linearly with
// pre-swizzled global src; ds_read applies the same XOR -> ~2-way banks.

#define BM 256
#define BN 256
#define BK 64

typedef __bf16 bf16x8 __attribute__((ext_vector_type(8)));
typedef __bf16 bf16x4 __attribute__((ext_vector_type(4)));
typedef float floatx4 __attribute__((ext_vector_type(4)));

__device__ __forceinline__ void async_ld16(const void* g, void* l) {
    __builtin_amdgcn_global_load_lds(
        (__attribute__((address_space(1))) void*)(g),
        (__attribute__((address_space(3))) void*)(l), 16, 0, 0);
}

#define BARX() __builtin_amdgcn_s_barrier()
#define SBAR0() __builtin_amdgcn_sched_barrier(0)
#define LGKM0() do { asm volatile("s_waitcnt lgkmcnt(0)" ::: "memory"); SBAR0(); } while (0)
#define VM6() asm volatile("s_waitcnt vmcnt(6)" ::: "memory")
#define VM0() asm volatile("s_waitcnt vmcnt(0)" ::: "memory")
#define NOPSTMT ((void)0)

// One C-quadrant x K=64: 4 m-frags x 2 n-frags x 2 k-steps = 16 MFMA.
// MH/NH compile-time so acc indexing stays static (rule #20: no scratch).
template <int MH, int NH>
__device__ __forceinline__ void mma_quad(floatx4 (&acc)[8][4],
                                         const bf16x8 (&af)[4][2],
                                         const bf16x8 (&bq)[2][2]) {
    __builtin_amdgcn_s_setprio(1);
#pragma unroll
    for (int i2 = 0; i2 < 4; ++i2)
#pragma unroll
        for (int j2 = 0; j2 < 2; ++j2)
#pragma unroll
            for (int ks = 0; ks < 2; ++ks)
                acc[MH * 4 + i2][NH * 2 + j2] =
                    __builtin_amdgcn_mfma_f32_16x16x32_bf16(
                        af[i2][ks], bq[j2][ks], acc[MH * 4 + i2][NH * 2 + j2],
                        0, 0, 0);
    __builtin_amdgcn_s_setprio(0);
}

// Fused basis + cvt (one launch instead of two).
// Cb[v*2048+q] = cos(pi*(2v+1)*q/4096), Sb = sin(same). Integer phase mod
// 8192 keeps the fp32 trig arg < 2*pi (exact in int32).
__global__ void prep_kernel(const float4* __restrict__ x, bf16x4* __restrict__ xb,
                            __bf16* __restrict__ Cb, __bf16* __restrict__ Sb) {
    int b = blockIdx.x;
    if (b < 16384) {
        int idx = b * 256 + threadIdx.x;
        int v = idx >> 11;
        int q = idx & 2047;
        int phase = ((2 * v + 1) * q) & 8191;
        float ang = (float)phase * 7.669903939428206e-04f;  // pi/4096
        Cb[idx] = (__bf16)__cosf(ang);
        Sb[idx] = (__bf16)__sinf(ang);
    } else {
        int i = (b - 16384) * 256 + threadIdx.x;
        float4 v = x[i];
        bf16x4 o;
        o[0] = (__bf16)v.x;
        o[1] = (__bf16)v.y;
        o[2] = (__bf16)v.z;
        o[3] = (__bf16)v.w;
        xb[i] = o;
    }
}

// NT GEMM: D[i*Ndim+j] = sum_k A[i*K+k] * B[j*K+k], per blockIdx.z batch.
template <typename OutT>
__global__ void __launch_bounds__(512, 2) gemm_nt8(
    const __bf16* __restrict__ A, const __bf16* __restrict__ B,
    OutT* __restrict__ D, int Ndim, int K,
    long batchA, long batchB, long batchD) {
    __shared__ __bf16 As[2][BM * BK];  // 2 x 32 KiB
    __shared__ __bf16 Bs[2][BN * BK];  // 2 x 32 KiB

    const int tid = threadIdx.x;
    const int lane = tid & 63;
    const int wave = tid >> 6;   // 0..7
    const int wr = wave >> 2;    // 0..1: row offset wr*128
    const int wc = wave & 3;     // 0..3: col offset wc*64

    A += batchA * blockIdx.z;
    B += batchB * blockIdx.z;
    D += batchD * blockIdx.z;

    const int row0 = blockIdx.y * BM;
    const int col0 = blockIdx.x * BN;

    // ---- staging addressing: one glds call = 512 thr x 16B = 64 rows.
    // Wave w writes 1 KiB at uniform base (w*512 elems); HW adds lane*16B,
    // so lane l -> row w*8 + (l>>3), chunk slot l&7. Global src pre-swizzled:
    // slot cs of row r fetches global chunk cs^(r&7).
    const int srow = tid >> 3;         // == wave*8 + (lane>>3)
    const int scs = tid & 7;
    const int sgc = scs ^ (srow & 7);  // global chunk for this slot
    const __bf16* aS = A + (size_t)(row0 + srow) * K + sgc * 8;
    const __bf16* bS = B + (size_t)(col0 + srow) * K + sgc * 8;
    const int ldsW = wave << 9;        // wave-uniform dest base (elems)

    // half: 0 = rows 0..127, 1 = rows 128..255 (2 glds per half-tile)
    auto STAGE_A = [&](int buf, int kt, int half) {
        const __bf16* s = aS + (size_t)(half * 128) * K + kt * BK;
        async_ld16(s, &As[buf][half * 128 * BK + ldsW]);
        async_ld16(s + (size_t)64 * K, &As[buf][(half * 128 + 64) * BK + ldsW]);
    };
    auto STAGE_B = [&](int buf, int kt, int half) {
        const __bf16* s = bS + (size_t)(half * 128) * K + kt * BK;
        async_ld16(s, &Bs[buf][half * 128 * BK + ldsW]);
        async_ld16(s + (size_t)64 * K, &Bs[buf][(half * 128 + 64) * BK + ldsW]);
    };

    // ---- fragment reads. A-frag: m=lane&15, k=(lane>>4)*8+j within each
    // 32-k step; global chunk = ks*4 + (lane>>4), read from slot chunk^(r&7).
    const int fr = lane & 15;
    const int fc = lane >> 4;
    const int c0 = fc ^ (fr & 7);
    const int k0off = c0 * 8;          // slot for k-step 0
    const int k1off = (c0 ^ 4) * 8;    // slot for k-step 1
    const int aBase = (wr * 128 + fr) * BK;
    const int bBase = (wc * 64 + fr) * BK;

    bf16x8 af[4][2], bl[2][2], bh[2][2];
    floatx4 acc[8][4] = {};

    auto LDA = [&](int buf, int mh) {
#pragma unroll
        for (int i2 = 0; i2 < 4; ++i2) {
            const int r = aBase + (mh * 4 + i2) * 16 * BK;
            af[i2][0] = *(const bf16x8*)&As[buf][r + k0off];
            af[i2][1] = *(const bf16x8*)&As[buf][r + k1off];
        }
    };
    auto LDB = [&](int buf, int nh, bf16x8(&bq)[2][2]) {
#pragma unroll
        for (int j2 = 0; j2 < 2; ++j2) {
            const int r = bBase + (nh * 2 + j2) * 16 * BK;
            bq[j2][0] = *(const bf16x8*)&Bs[buf][r + k0off];
            bq[j2][1] = *(const bf16x8*)&Bs[buf][r + k1off];
        }
    };

    // 4 phases of one K-tile: quadrants (0,0)->(0,1)->(1,1)->(1,0);
    // S1..S4 are the per-phase half-tile stage issues, VMW the end wait.
    // Stage-issue points sit strictly after each LDS region's last-reader
    // barrier (B-lo read ph1, B-hi ph2, A-lo ph1, A-hi ph3).
#define TILE4(buf, S1, S2, S3, S4, VMW) do {               \
        LDA(buf, 0); LDB(buf, 0, bl); S1; BARX(); LGKM0(); \
        mma_quad<0, 0>(acc, af, bl); BARX();               \
        LDB(buf, 1, bh); S2; BARX(); LGKM0();              \
        mma_quad<0, 1>(acc, af, bh); BARX();               \
        LDA(buf, 1); S3; BARX(); LGKM0();                  \
        mma_quad<1, 1>(acc, af, bh); BARX();               \
        S4; BARX();                                        \
        mma_quad<1, 0>(acc, af, bl); VMW; BARX();          \
    } while (0)

    const int nT = K / BK;      // 32 K-tiles
    const int nPairs = nT / 2;  // 16

    // Prologue: tile0 fully (B-lo,B-hi,A-lo,A-hi) + tile1's first 3 halves
    // = 14 glds; vmcnt(6) retires tile0's 8, leaves tile1.{Blo,Bhi,Alo}.
    STAGE_B(0, 0, 0); STAGE_B(0, 0, 1); STAGE_A(0, 0, 0); STAGE_A(0, 0, 1);
    STAGE_B(1, 1, 0); STAGE_B(1, 1, 1); STAGE_A(1, 1, 0);
    VM6();
    BARX();

    // Steady state: iter i computes tiles t=2i (buf0) and t+1 (buf1);
    // stage stream runs 7 halves ahead; vmcnt(6) at phases 4 and 8
    // guarantees tile t+1 landed before its buffer is read.
    for (int i = 0; i < nPairs - 1; ++i) {
        const int t = 2 * i;
        TILE4(0, STAGE_A(1, t + 1, 1),   // t+1.A-hi (completes t+1)
                 STAGE_B(0, t + 2, 0),   // t+2.B-lo
                 STAGE_B(0, t + 2, 1),   // t+2.B-hi
                 STAGE_A(0, t + 2, 0),   // t+2.A-lo
                 VM6());
        TILE4(1, STAGE_A(0, t + 2, 1),   // t+2.A-hi
                 STAGE_B(1, t + 3, 0),
                 STAGE_B(1, t + 3, 1),
                 STAGE_A(1, t + 3, 0),
                 VM6());
    }
    // Peeled last pair (tiles nT-2, nT-1): finish nT-1's staging, drain.
    TILE4(0, STAGE_A(1, nT - 1, 1), NOPSTMT, NOPSTMT, NOPSTMT, VM0());
    TILE4(1, NOPSTMT, NOPSTMT, NOPSTMT, NOPSTMT, NOPSTMT);
#undef TILE4

    // Epilogue: C/D layout col=lane&15, row=(lane>>4)*4+reg (verified R1).
    const int ecol = lane & 15;
    const int erow = (lane >> 4) * 4;
#pragma unroll
    for (int i = 0; i < 8; ++i)
#pragma unroll
        for (int j = 0; j < 4; ++j)
#pragma unroll
            for (int r = 0; r < 4; ++r) {
                int gi = row0 + wr * 128 + i * 16 + erow + r;
                int gj = col0 + wc * 64 + j * 16 + ecol;
                D[(size_t)gi * Ndim + gj] = (OutT)acc[i][j][r];
            }
}

extern "C" void kernel_launch(void* const* d_in, const int* in_sizes, int n_in,
                              void* d_out, int out_size, void* d_ws, size_t ws_size,
                              hipStream_t stream) {
    const float* x = (const float*)d_in[0];
    float* out = (float*)d_out;

    const int MN = 2048;
    const size_t mat = (size_t)MN * MN;  // 4M elems
    const size_t bmat = 4 * mat;         // 16M elems (B=4)

    // Workspace layout (80 MiB total):
    __bf16* Cb = (__bf16*)d_ws;   //  8 MiB
    __bf16* Sb = Cb + mat;        //  8 MiB
    __bf16* xb = Sb + mat;        // 32 MiB
    __bf16* tT = xb + bmat;       // 32 MiB

    // basis (16384 blocks) + cvt (16384 blocks) fused into one launch
    prep_kernel<<<32768, 256, 0, stream>>>((const float4*)x, (bf16x4*)xb, Cb, Sb);

    dim3 grid(MN / BN, MN / BM, 4);  // (8, 8, 4) = 256 blocks, 1/CU
    // pass1: tT[b][v][p] = sum_q C[v][q] * xb[b][p][q]
    gemm_nt8<__bf16><<<grid, 512, 0, stream>>>(Cb, xb, tT, MN, MN,
                                               0L, (long)mat, (long)mat);
    // pass2: out[b][u][v] = sum_p S[u][p] * tT[b][v][p]
    gemm_nt8<float><<<grid, 512, 0, stream>>>(Sb, tT, out, MN, MN,
                                              0L, (long)mat, (long)mat);
}

// Round 3
// 197.259 us; speedup vs baseline: 1.3043x; 1.2060x over previous
//
#include <hip/hip_runtime.h>
#include <hip/hip_bf16.h>
#include <math.h>

// IDSCT2: out[b,u,v] = sum_{p,q} x[b,p,q] * S[u,p] * C[v,q]
// R8: parity-folded GEMMs (2x FLOP reduction per pass).
//   C[2047-v,q] = (-1)^q C[v,q];  S[2047-u,p] = -(-1)^p S[u,p]
// pass1: Et[v'][p] = sum_j Ce[v'][j] xe[p][j], Ot likewise (odd q);
//        tT[v'] = Et+Ot, tT[2047-v'] = Et-Ot, written p-parity-split as
//        tTe[v][m]=tT[v][2m], tTo[v][m]=tT[v][2m+1] (feeds pass2 directly).
// pass2: E2[u'][v] = sum_m Se[u'][m] tTe[v][m], O2 likewise;
//        out[u'] = E2+O2, out[2047-u'] = O2-E2 (exact fp32 fold).
// Each block carries accE+accO (128 AGPR) and stages 4 sub-tiles
// (Ae,Ao,Be,Bo) per BK=32 K-step into TRIPLE-buffered LDS (3 x 48 KiB);
// 2 phases/tile ({8 ds_read_b128, 3 glds, bar, lgkm0+schedbar, 16 MFMA,
// bar}), vmcnt(6) at tile end only (stage t+2 while computing t).
// Swizzle: 64B rows = 4 chunks; slot = chunk ^ ((row>>1)&3) via
// pre-swizzled global src (linear glds dest) -> uniform 2-way banks.

#define BM 128   // output rows per block (v' / u')
#define BN 256   // output cols per block (p / v)
#define BK 32
#define KDIM 1024

typedef __bf16 bf16x8 __attribute__((ext_vector_type(8)));
typedef __bf16 bf16x4 __attribute__((ext_vector_type(4)));
typedef float floatx4 __attribute__((ext_vector_type(4)));

__device__ __forceinline__ void async_ld16(const void* g, void* l) {
    __builtin_amdgcn_global_load_lds(
        (__attribute__((address_space(1))) void*)(g),
        (__attribute__((address_space(3))) void*)(l), 16, 0, 0);
}

#define BARX() __builtin_amdgcn_s_barrier()
#define SBAR0() __builtin_amdgcn_sched_barrier(0)
#define LGKM0() do { asm volatile("s_waitcnt lgkmcnt(0)" ::: "memory"); SBAR0(); } while (0)
#define VM6() asm volatile("s_waitcnt vmcnt(6)" ::: "memory")
#define VM0() asm volatile("s_waitcnt vmcnt(0)" ::: "memory")
#define NOPSTMT ((void)0)

// Basis + deinterleave-convert x. Integer phase mod 8192 keeps trig arg
// exact: arg = pi/4096 * phase.
//   Ce[v',j]=cos(pi(2v'+1)(2j)/4096)   Co: (2j+1)
//   Se[u',m]=sin(pi(2u'+1)(2m)/4096)   So: (2m+1)
//   xe[b,p,m]=x[b,p,2m]  xo: 2m+1
__global__ void prep_kernel(const float4* __restrict__ x,
                            bf16x4* __restrict__ xe, bf16x4* __restrict__ xo,
                            __bf16* __restrict__ Ce, __bf16* __restrict__ Co,
                            __bf16* __restrict__ Se, __bf16* __restrict__ So) {
    int b = blockIdx.x;
    if (b < 4096) {  // 1M basis entries
        int idx = b * 256 + threadIdx.x;
        int vp = idx >> 10;
        int j = idx & 1023;
        int pe = ((2 * vp + 1) * (2 * j)) & 8191;
        int po = ((2 * vp + 1) * (2 * j + 1)) & 8191;
        float ae = (float)pe * 7.669903939428206e-04f;  // pi/4096
        float ao = (float)po * 7.669903939428206e-04f;
        float se, ce, so, co;
        __sincosf(ae, &se, &ce);
        __sincosf(ao, &so, &co);
        Ce[idx] = (__bf16)ce;
        Co[idx] = (__bf16)co;
        Se[idx] = (__bf16)se;
        So[idx] = (__bf16)so;
    } else {  // 2M threads, 8 floats each
        int g = (b - 4096) * 256 + threadIdx.x;
        float4 v0 = x[2 * g];
        float4 v1 = x[2 * g + 1];
        bf16x4 e, o;
        e[0] = (__bf16)v0.x; e[1] = (__bf16)v0.z;
        e[2] = (__bf16)v1.x; e[3] = (__bf16)v1.z;
        o[0] = (__bf16)v0.y; o[1] = (__bf16)v0.w;
        o[2] = (__bf16)v1.y; o[3] = (__bf16)v1.w;
        xe[g] = e;
        xo[g] = o;
    }
}

// Parity-folded NT GEMM. A{e,o}: [1024][1024] (shared over z).
// B{e,o}: [z][2048][1024]. PASS=1: D0/D1 = tTe/tTo [z][2048][1024] bf16,
// fold rows v', 2047-v' and split output cols by parity.
// PASS=2: Df = out [z][2048][2048] fp32, fold rows u', 2047-u'.
template <int PASS>
__global__ void __launch_bounds__(512, 2) gemm_eo(
    const __bf16* __restrict__ Ae, const __bf16* __restrict__ Ao,
    const __bf16* __restrict__ Be, const __bf16* __restrict__ Bo,
    __bf16* __restrict__ D0, __bf16* __restrict__ D1,
    float* __restrict__ Df) {
    // per buffer: Ae[128*32] Ao[128*32] Be[256*32] Bo[256*32] = 24576 elems
    __shared__ __bf16 lds[3][24576];  // 144 KiB
    constexpr int OFF_AE = 0, OFF_AO = 4096, OFF_BE = 8192, OFF_BO = 16384;

    const int tid = threadIdx.x;
    const int lane = tid & 63;
    const int wave = tid >> 6;   // 0..7
    const int wr = wave >> 2;    // 0..1: row offset wr*64
    const int wc = wave & 3;     // 0..3: col offset wc*64

    const size_t zB = (size_t)blockIdx.z * 2048 * 1024;
    Be += zB; Bo += zB;

    const int row0 = blockIdx.y * BM;   // v'/u' in [0,1024)
    const int col0 = blockIdx.x * BN;   // p/v  in [0,2048)

    // ---- staging: one glds = 512 thr x 16B = 8 KiB = 128 rows of 64B.
    // lane slot within 16-row window freely assignable -> choose
    // global chunk = slot ^ ((row>>1)&3) (involution, shared with reads).
    const int srow = tid >> 2;
    const int scs = tid & 3;
    const int sgc = (scs ^ ((srow >> 1) & 3)) * 8;
    const __bf16* aeS = Ae + (size_t)(row0 + srow) * KDIM + sgc;
    const __bf16* aoS = Ao + (size_t)(row0 + srow) * KDIM + sgc;
    const __bf16* beS = Be + (size_t)(col0 + srow) * KDIM + sgc;
    const __bf16* boS = Bo + (size_t)(col0 + srow) * KDIM + sgc;
    const int ldsW = wave << 9;  // wave-uniform dest base (elems)

    auto STG_E = [&](int s, int kt) {
        async_ld16(aeS + kt * BK, &lds[s][OFF_AE + ldsW]);
        async_ld16(beS + kt * BK, &lds[s][OFF_BE + ldsW]);
        async_ld16(beS + kt * BK + (size_t)128 * KDIM,
                   &lds[s][OFF_BE + 4096 + ldsW]);
    };
    auto STG_O = [&](int s, int kt) {
        async_ld16(aoS + kt * BK, &lds[s][OFF_AO + ldsW]);
        async_ld16(boS + kt * BK, &lds[s][OFF_BO + ldsW]);
        async_ld16(boS + kt * BK + (size_t)128 * KDIM,
                   &lds[s][OFF_BO + 4096 + ldsW]);
    };

    // ---- fragment reads: m/n = lane&15 (+16*frag), k-chunk = lane>>4;
    // stored slot = chunk ^ ((fr>>1)&3) (frag row offsets are mult of 16
    // so only fr enters the swizzle) -> uniform 2-way banking.
    const int fr = lane & 15;
    const int fc = lane >> 4;
    const int slotOff = (fc ^ ((fr >> 1) & 3)) * 8;
    const int aBase = (wr * 64 + fr) * BK + slotOff;
    const int bBase = (wc * 64 + fr) * BK + slotOff;

    bf16x8 afr[4], bfr[4];
    floatx4 accE[4][4] = {};
    floatx4 accO[4][4] = {};

    auto LDF = [&](const __bf16* buf, int aOff, int bOff) {
#pragma unroll
        for (int i = 0; i < 4; ++i)
            afr[i] = *(const bf16x8*)&buf[aOff + aBase + i * 16 * BK];
#pragma unroll
        for (int j = 0; j < 4; ++j)
            bfr[j] = *(const bf16x8*)&buf[bOff + bBase + j * 16 * BK];
    };
    auto MMA16 = [&](floatx4(&acc)[4][4]) {
        __builtin_amdgcn_s_setprio(1);
#pragma unroll
        for (int i = 0; i < 4; ++i)
#pragma unroll
            for (int j = 0; j < 4; ++j)
                acc[i][j] = __builtin_amdgcn_mfma_f32_16x16x32_bf16(
                    afr[i], bfr[j], acc[i][j], 0, 0, 0);
        __builtin_amdgcn_s_setprio(0);
    };

    // Tile = 2 phases (E then O), 16 MFMA + 8 ds_read + 3 glds each.
    // Triple-buffered: stage touches neither live buffer -> barriers are
    // cadence/coherence only; vmcnt(6) at tile end retires tile t+1.
#define TILE(bc, SE, SO, VMW) do {                     \
        LDF(lds[bc], OFF_AE, OFF_BE); SE;              \
        BARX(); LGKM0();                               \
        MMA16(accE); BARX();                           \
        LDF(lds[bc], OFF_AO, OFF_BO); SO;              \
        BARX(); LGKM0();                               \
        MMA16(accO); VMW; BARX();                      \
    } while (0)

    // Prologue: tiles 0,1 staged (12 glds); vmcnt(6) retires tile 0.
    STG_E(0, 0); STG_O(0, 0);
    STG_E(1, 1); STG_O(1, 1);
    VM6();
    BARX();

    // 32 K-tiles; unroll by 3 for static buffer indices (t%3).
    for (int i = 0; i < 10; ++i) {
        const int t = 3 * i;
        TILE(0, STG_E(2, t + 2), STG_O(2, t + 2), VM6());
        TILE(1, STG_E(0, t + 3), STG_O(0, t + 3), VM6());
        TILE(2, STG_E(1, t + 4), STG_O(1, t + 4), VM6());
    }
    TILE(0, NOPSTMT, NOPSTMT, VM0());   // tile 30
    TILE(1, NOPSTMT, NOPSTMT, NOPSTMT); // tile 31
#undef TILE

    // Epilogue. C/D layout: col=lane&15, row=(lane>>4)*4+reg (verified R1).
    const int ecol = lane & 15;
    const int erow = (lane >> 4) * 4;
#pragma unroll
    for (int i = 0; i < 4; ++i)
#pragma unroll
        for (int j = 0; j < 4; ++j)
#pragma unroll
            for (int r = 0; r < 4; ++r) {
                const int gi = row0 + wr * 64 + i * 16 + erow + r;
                const int gj = col0 + wc * 64 + j * 16 + ecol;
                const float e = accE[i][j][r];
                const float o = accO[i][j][r];
                if (PASS == 1) {
                    // tT[gi] = e+o ; tT[2047-gi] = e-o ; split col parity
                    __bf16* base = (gj & 1) ? D1 : D0;
                    base += zB;
                    const size_t m = (size_t)(gj >> 1);
                    base[(size_t)gi * 1024 + m] = (__bf16)(e + o);
                    base[(size_t)(2047 - gi) * 1024 + m] = (__bf16)(e - o);
                } else {
                    // out[gi] = e+o ; out[2047-gi] = o-e
                    float* ob = Df + (size_t)blockIdx.z * 2048 * 2048;
                    ob[(size_t)gi * 2048 + gj] = e + o;
                    ob[(size_t)(2047 - gi) * 2048 + gj] = o - e;
                }
            }
}

extern "C" void kernel_launch(void* const* d_in, const int* in_sizes, int n_in,
                              void* d_out, int out_size, void* d_ws, size_t ws_size,
                              hipStream_t stream) {
    const float* x = (const float*)d_in[0];
    float* out = (float*)d_out;

    const size_t m1 = (size_t)1024 * 1024;  // basis elems (2 MiB each)
    const size_t hm = (size_t)4 * 2048 * 1024;  // half-matrix batch: 8M elems

    // Workspace (72 MiB): Ce,Co,Se,So (8 MiB) | xe,xo (32) | tTe,tTo (32)
    __bf16* Ce = (__bf16*)d_ws;
    __bf16* Co = Ce + m1;
    __bf16* Se = Co + m1;
    __bf16* So = Se + m1;
    __bf16* xe = So + m1;
    __bf16* xo = xe + hm;
    __bf16* tTe = xo + hm;
    __bf16* tTo = tTe + hm;

    // 4096 basis blocks + 8192 deinterleave blocks
    prep_kernel<<<12288, 256, 0, stream>>>((const float4*)x, (bf16x4*)xe,
                                           (bf16x4*)xo, Ce, Co, Se, So);

    dim3 grid(2048 / BN, 1024 / BM, 4);  // (8, 8, 4) = 256 blocks
    // pass1: Et/Ot over q-parity; epilogue folds v' and splits p-parity
    gemm_eo<1><<<grid, 512, 0, stream>>>(Ce, Co, xe, xo, tTe, tTo, nullptr);
    // pass2: E2/O2 over p-parity; epilogue folds u', writes fp32 out
    gemm_eo<2><<<grid, 512, 0, stream>>>(Se, So, tTe, tTo, nullptr, nullptr, out);
}

// Round 4
// 190.831 us; speedup vs baseline: 1.3483x; 1.0337x over previous
//
#include <hip/hip_runtime.h>
#include <hip/hip_bf16.h>
#include <math.h>

// IDSCT2: out[b,u,v] = sum_{p,q} x[b,p,q] * S[u,p] * C[v,q]
// R9: parity-folded GEMMs (R8 math, verified) with a single-barrier
// K-loop: triple-buffered LDS makes stage(t+2) / compute(t) disjoint, so
// each K-tile needs exactly ONE s_barrier. Per tile:
//   LDF_E (8 ds_read_b128) ; STG_E(t+2) (3 glds) ; lgkm0+schedbar ;
//   16 MFMA (E) ; LDF_O ; STG_O(t+2) ; lgkm0 ; 16 MFMA (O) ;
//   vmcnt(6) ; s_barrier
// vmcnt(6)-then-barrier retires tile t+1's 6 glds in EVERY wave and
// publishes before any wave reads buf (t+1)%3 (per-wave ledger: steady
// state has t+1(6)+t+2(6)=12 outstanding at the wait). Barriers/dispatch
// drop 128 -> 33; 32 MFMA per barrier (AITER-class cadence); the long
// barrier-free stretch gives the 2 waves/SIMD role-split that setprio
// arbitrates.
//   C[2047-v,q] = (-1)^q C[v,q];  S[2047-u,p] = -(-1)^p S[u,p]
// pass1: Et/Ot (even/odd q), tT[v']=Et+Ot, tT[2047-v']=Et-Ot, output
// p-parity-split (tTe/tTo) to feed pass2 directly.
// pass2: E2/O2 (even/odd p), out[u']=E2+O2, out[2047-u']=O2-E2 (fp32).
// Swizzle (both-sides, rule #21): 64B rows = 4 chunks; slot =
// chunk ^ ((row>>1)&3) via pre-swizzled global src (linear glds dest);
// ds_read applies the same XOR -> conflict-free b128 (R8 measured 0).

#define BM 128   // output rows per block (v' / u')
#define BN 256   // output cols per block (p / v)
#define BK 32
#define KDIM 1024

typedef __bf16 bf16x8 __attribute__((ext_vector_type(8)));
typedef __bf16 bf16x4 __attribute__((ext_vector_type(4)));
typedef float floatx4 __attribute__((ext_vector_type(4)));

__device__ __forceinline__ void async_ld16(const void* g, void* l) {
    __builtin_amdgcn_global_load_lds(
        (__attribute__((address_space(1))) void*)(g),
        (__attribute__((address_space(3))) void*)(l), 16, 0, 0);
}

#define BARX() __builtin_amdgcn_s_barrier()
#define SBAR0() __builtin_amdgcn_sched_barrier(0)
#define LGKM0() do { asm volatile("s_waitcnt lgkmcnt(0)" ::: "memory"); SBAR0(); } while (0)
#define VM6() do { asm volatile("s_waitcnt vmcnt(6)" ::: "memory"); SBAR0(); } while (0)
#define VM0() do { asm volatile("s_waitcnt vmcnt(0)" ::: "memory"); SBAR0(); } while (0)
#define NOPSTMT ((void)0)

// Basis + deinterleave-convert x. Integer phase mod 8192 keeps trig arg
// exact: arg = pi/4096 * phase.
//   Ce[v',j]=cos(pi(2v'+1)(2j)/4096)   Co: (2j+1)
//   Se[u',m]=sin(pi(2u'+1)(2m)/4096)   So: (2m+1)
//   xe[b,p,m]=x[b,p,2m]  xo: 2m+1
__global__ void prep_kernel(const float4* __restrict__ x,
                            bf16x4* __restrict__ xe, bf16x4* __restrict__ xo,
                            __bf16* __restrict__ Ce, __bf16* __restrict__ Co,
                            __bf16* __restrict__ Se, __bf16* __restrict__ So) {
    int b = blockIdx.x;
    if (b < 4096) {  // 1M basis entries
        int idx = b * 256 + threadIdx.x;
        int vp = idx >> 10;
        int j = idx & 1023;
        int pe = ((2 * vp + 1) * (2 * j)) & 8191;
        int po = ((2 * vp + 1) * (2 * j + 1)) & 8191;
        float ae = (float)pe * 7.669903939428206e-04f;  // pi/4096
        float ao = (float)po * 7.669903939428206e-04f;
        float se, ce, so, co;
        __sincosf(ae, &se, &ce);
        __sincosf(ao, &so, &co);
        Ce[idx] = (__bf16)ce;
        Co[idx] = (__bf16)co;
        Se[idx] = (__bf16)se;
        So[idx] = (__bf16)so;
    } else {  // 2M threads, 8 floats each
        int g = (b - 4096) * 256 + threadIdx.x;
        float4 v0 = x[2 * g];
        float4 v1 = x[2 * g + 1];
        bf16x4 e, o;
        e[0] = (__bf16)v0.x; e[1] = (__bf16)v0.z;
        e[2] = (__bf16)v1.x; e[3] = (__bf16)v1.z;
        o[0] = (__bf16)v0.y; o[1] = (__bf16)v0.w;
        o[2] = (__bf16)v1.y; o[3] = (__bf16)v1.w;
        xe[g] = e;
        xo[g] = o;
    }
}

// Parity-folded NT GEMM. A{e,o}: [1024][1024] (shared over z).
// B{e,o}: [z][2048][1024]. PASS=1: D0/D1 = tTe/tTo [z][2048][1024] bf16,
// fold rows v', 2047-v' and split output cols by parity.
// PASS=2: Df = out [z][2048][2048] fp32, fold rows u', 2047-u'.
template <int PASS>
__global__ void __launch_bounds__(512, 2) gemm_eo(
    const __bf16* __restrict__ Ae, const __bf16* __restrict__ Ao,
    const __bf16* __restrict__ Be, const __bf16* __restrict__ Bo,
    __bf16* __restrict__ D0, __bf16* __restrict__ D1,
    float* __restrict__ Df) {
    // per buffer: Ae[128*32] Ao[128*32] Be[256*32] Bo[256*32] = 24576 elems
    __shared__ __bf16 lds[3][24576];  // 144 KiB
    constexpr int OFF_AE = 0, OFF_AO = 4096, OFF_BE = 8192, OFF_BO = 16384;

    const int tid = threadIdx.x;
    const int lane = tid & 63;
    const int wave = tid >> 6;   // 0..7
    const int wr = wave >> 2;    // 0..1: row offset wr*64
    const int wc = wave & 3;     // 0..3: col offset wc*64

    const size_t zB = (size_t)blockIdx.z * 2048 * 1024;
    Be += zB; Bo += zB;

    const int row0 = blockIdx.y * BM;   // v'/u' in [0,1024)
    const int col0 = blockIdx.x * BN;   // p/v  in [0,2048)

    // ---- staging: one glds = 512 thr x 16B = 8 KiB = 128 rows of 64B.
    // lane slot within 16-row window freely assignable -> choose
    // global chunk = slot ^ ((row>>1)&3) (involution, shared with reads).
    const int srow = tid >> 2;
    const int scs = tid & 3;
    const int sgc = (scs ^ ((srow >> 1) & 3)) * 8;
    const __bf16* aeS = Ae + (size_t)(row0 + srow) * KDIM + sgc;
    const __bf16* aoS = Ao + (size_t)(row0 + srow) * KDIM + sgc;
    const __bf16* beS = Be + (size_t)(col0 + srow) * KDIM + sgc;
    const __bf16* boS = Bo + (size_t)(col0 + srow) * KDIM + sgc;
    const int ldsW = wave << 9;  // wave-uniform dest base (elems)

    auto STG_E = [&](int s, int kt) {
        async_ld16(aeS + kt * BK, &lds[s][OFF_AE + ldsW]);
        async_ld16(beS + kt * BK, &lds[s][OFF_BE + ldsW]);
        async_ld16(beS + kt * BK + (size_t)128 * KDIM,
                   &lds[s][OFF_BE + 4096 + ldsW]);
    };
    auto STG_O = [&](int s, int kt) {
        async_ld16(aoS + kt * BK, &lds[s][OFF_AO + ldsW]);
        async_ld16(boS + kt * BK, &lds[s][OFF_BO + ldsW]);
        async_ld16(boS + kt * BK + (size_t)128 * KDIM,
                   &lds[s][OFF_BO + 4096 + ldsW]);
    };

    // ---- fragment reads: m/n = lane&15 (+16*frag), k-chunk = lane>>4;
    // stored slot = chunk ^ ((fr>>1)&3) (frag row offsets are mult of 16
    // so only fr enters the swizzle) -> conflict-free b128 (R8: 0).
    const int fr = lane & 15;
    const int fc = lane >> 4;
    const int slotOff = (fc ^ ((fr >> 1) & 3)) * 8;
    const int aBase = (wr * 64 + fr) * BK + slotOff;
    const int bBase = (wc * 64 + fr) * BK + slotOff;

    bf16x8 afr[4], bfr[4];
    floatx4 accE[4][4] = {};
    floatx4 accO[4][4] = {};

    auto LDF = [&](const __bf16* buf, int aOff, int bOff) {
#pragma unroll
        for (int i = 0; i < 4; ++i)
            afr[i] = *(const bf16x8*)&buf[aOff + aBase + i * 16 * BK];
#pragma unroll
        for (int j = 0; j < 4; ++j)
            bfr[j] = *(const bf16x8*)&buf[bOff + bBase + j * 16 * BK];
    };
    auto MMA16 = [&](floatx4(&acc)[4][4]) {
        __builtin_amdgcn_s_setprio(1);
#pragma unroll
        for (int i = 0; i < 4; ++i)
#pragma unroll
            for (int j = 0; j < 4; ++j)
                acc[i][j] = __builtin_amdgcn_mfma_f32_16x16x32_bf16(
                    afr[i], bfr[j], acc[i][j], 0, 0, 0);
        __builtin_amdgcn_s_setprio(0);
    };

    // One K-tile = one barrier. Triple buffer: compute buf t%3 while
    // tile t+2 stages into (t+2)%3 (disjoint). End-of-tile vmcnt(6)
    // retires tile t+1's 6 glds (per-wave), then the barrier publishes
    // them to all waves before buf (t+1)%3 is read next tile.
#define TILE(bc, SE, SO, VMW) do {                     \
        LDF(lds[bc], OFF_AE, OFF_BE); SE; LGKM0();     \
        MMA16(accE);                                   \
        LDF(lds[bc], OFF_AO, OFF_BO); SO; LGKM0();     \
        MMA16(accO); VMW; BARX();                      \
    } while (0)

    // Prologue: tiles 0,1 staged (12 glds); vmcnt(6) retires tile 0.
    STG_E(0, 0); STG_O(0, 0);
    STG_E(1, 1); STG_O(1, 1);
    VM6();
    BARX();

    // 32 K-tiles; unroll by 3 for static buffer indices (t%3).
    for (int i = 0; i < 10; ++i) {
        const int t = 3 * i;
        TILE(0, STG_E(2, t + 2), STG_O(2, t + 2), VM6());
        TILE(1, STG_E(0, t + 3), STG_O(0, t + 3), VM6());
        TILE(2, STG_E(1, t + 4), STG_O(1, t + 4), VM6());
    }
    TILE(0, NOPSTMT, NOPSTMT, VM0());   // tile 30: drain tile 31's glds
    TILE(1, NOPSTMT, NOPSTMT, NOPSTMT); // tile 31
#undef TILE

    // Epilogue. C/D layout: col=lane&15, row=(lane>>4)*4+reg (verified R1).
    const int ecol = lane & 15;
    const int erow = (lane >> 4) * 4;
#pragma unroll
    for (int i = 0; i < 4; ++i)
#pragma unroll
        for (int j = 0; j < 4; ++j)
#pragma unroll
            for (int r = 0; r < 4; ++r) {
                const int gi = row0 + wr * 64 + i * 16 + erow + r;
                const int gj = col0 + wc * 64 + j * 16 + ecol;
                const float e = accE[i][j][r];
                const float o = accO[i][j][r];
                if (PASS == 1) {
                    // tT[gi] = e+o ; tT[2047-gi] = e-o ; split col parity
                    __bf16* base = (gj & 1) ? D1 : D0;
                    base += zB;
                    const size_t m = (size_t)(gj >> 1);
                    base[(size_t)gi * 1024 + m] = (__bf16)(e + o);
                    base[(size_t)(2047 - gi) * 1024 + m] = (__bf16)(e - o);
                } else {
                    // out[gi] = e+o ; out[2047-gi] = o-e
                    float* ob = Df + (size_t)blockIdx.z * 2048 * 2048;
                    ob[(size_t)gi * 2048 + gj] = e + o;
                    ob[(size_t)(2047 - gi) * 2048 + gj] = o - e;
                }
            }
}

extern "C" void kernel_launch(void* const* d_in, const int* in_sizes, int n_in,
                              void* d_out, int out_size, void* d_ws, size_t ws_size,
                              hipStream_t stream) {
    const float* x = (const float*)d_in[0];
    float* out = (float*)d_out;

    const size_t m1 = (size_t)1024 * 1024;  // basis elems (2 MiB each)
    const size_t hm = (size_t)4 * 2048 * 1024;  // half-matrix batch: 8M elems

    // Workspace (72 MiB): Ce,Co,Se,So (8 MiB) | xe,xo (32) | tTe,tTo (32)
    __bf16* Ce = (__bf16*)d_ws;
    __bf16* Co = Ce + m1;
    __bf16* Se = Co + m1;
    __bf16* So = Se + m1;
    __bf16* xe = So + m1;
    __bf16* xo = xe + hm;
    __bf16* tTe = xo + hm;
    __bf16* tTo = tTe + hm;

    // 4096 basis blocks + 8192 deinterleave blocks
    prep_kernel<<<12288, 256, 0, stream>>>((const float4*)x, (bf16x4*)xe,
                                           (bf16x4*)xo, Ce, Co, Se, So);

    dim3 grid(2048 / BN, 1024 / BM, 4);  // (8, 8, 4) = 256 blocks
    // pass1: Et/Ot over q-parity; epilogue folds v' and splits p-parity
    gemm_eo<1><<<grid, 512, 0, stream>>>(Ce, Co, xe, xo, tTe, tTo, nullptr);
    // pass2: E2/O2 over p-parity; epilogue folds u', writes fp32 out
    gemm_eo<2><<<grid, 512, 0, stream>>>(Se, So, tTe, tTo, nullptr, nullptr, out);
}